// Round 7
// baseline (17139.845 us; speedup 1.0000x reference)
//
#include <hip/hip_runtime.h>

#define TT 2048
#define BB 512
#define II 5
#define HH 64
#define NTHR 768

__device__ __forceinline__ float sigm(float v)   { return 1.0f / (1.0f + __expf(-v)); }
__device__ __forceinline__ float tanh_f(float v) { return 1.0f - 2.0f / (1.0f + __expf(2.0f * v)); }

// 768 threads = 3 groups x 256 rows; one batch elem per block; grid 512.
// Thread (g,r) holds ONE 64-float weight row in registers:
//   g0: W_hh0[r,:]   g1: W_ih1[r,:]   g2: W_hh1[r,:]
// Live set ~80 VGPR, designed under the 84-VGPR budget that
// __launch_bounds__(768,3) was MEASURED to yield in R4 (2 blocks/CU).
// No waves_per_eu (R5: budget 40, disaster), no KEEP (R2/R3: spills).
__global__ __launch_bounds__(NTHR, 3) void lstm2_kernel(
    const float* __restrict__ x,
    const float* __restrict__ W_ih0, const float* __restrict__ W_hh0,
    const float* __restrict__ b_ih0, const float* __restrict__ b_hh0,
    const float* __restrict__ W_ih1, const float* __restrict__ W_hh1,
    const float* __restrict__ b_ih1, const float* __restrict__ b_hh1,
    const float* __restrict__ W_out, const float* __restrict__ b_out,
    float* __restrict__ out)
{
    const int t    = threadIdx.x;
    const int b    = blockIdx.x;
    const int g    = t >> 8;        // 0: Whh0  1: Wih1  2: Whh1
    const int r    = t & 255;
    const int gate = r >> 6;        // 0=i 1=f 2=g 3=o (g0 path)

    __shared__ __align__(16) float h1s[HH];
    __shared__ __align__(16) float h2s[HH];
    __shared__ __align__(16) float act0[256];   // layer-0 gates (activated)
    __shared__ __align__(16) float pB[256];     // Wih1 . h1
    __shared__ __align__(16) float pC[256];     // Whh1 . h2
    __shared__ float bias0s[256];
    __shared__ float bias1s[256];
    __shared__ float wih0T[II][256];            // W_ih0 transposed (lane-distinct, conflict-free)
    __shared__ float xst[2][8];                 // staged x, double-buffered

    // ---- one 64-float weight row per thread ----
    const float* Wrow = (g == 0) ? (W_hh0 + r * HH)
                       : (g == 1) ? (W_ih1 + r * HH)
                                  : (W_hh1 + r * HH);
    float4 w[16];
    #pragma unroll
    for (int k = 0; k < 16; ++k) w[k] = ((const float4*)Wrow)[k];

    if (t < 256) {
        bias0s[t] = b_ih0[t] + b_hh0[t];
        bias1s[t] = b_ih1[t] + b_hh1[t];
        #pragma unroll
        for (int k = 0; k < II; ++k) wih0T[k][t] = W_ih0[t * II + k];
    }
    if (t < HH) { h1s[t] = 0.0f; h2s[t] = 0.0f; }

    const float* xb = x + (size_t)b * II;
    if (t < II) xst[0][t] = xb[t];

    float c = 0.0f;   // c1 on wave0 (t<64), c2 on wave1 (64<=t<128)
    __syncthreads();

    // Pipelined schedule (R3/R4-verified): iter s computes gates0[s]
    // (vs h1[s-1]) and gates1[s-1] partials (vs h1[s-1], h2[s-2]);
    // update writes h1[s], h2[s-1]. Two barriers per step.
    for (int s = 0; s <= TT; ++s) {
        // issue next x load early (5 lanes), LDS-write late
        float xnv = 0.0f;
        if (t < II) {
            const int sn = (s + 1 < TT) ? (s + 1) : (TT - 1);
            xnv = xb[(size_t)sn * (BB * II) + t];
        }

        // ---- 64-FMA broadcast dot: 16 chunks of one b128, 2 alt accumulators.
        // sched_barrier between chunks caps ds_read hoisting (register pressure).
        const float4* hp = (g == 2) ? (const float4*)h2s : (const float4*)h1s;
        float acca = 0.0f, accb = 0.0f;
        #define DOT1A(k0)                                   \
        {                                                   \
            float4 hv = hp[k0];                             \
            acca = fmaf(hv.x, w[k0].x, acca);               \
            acca = fmaf(hv.y, w[k0].y, acca);               \
            acca = fmaf(hv.z, w[k0].z, acca);               \
            acca = fmaf(hv.w, w[k0].w, acca);               \
        }
        #define DOT1B(k0)                                   \
        {                                                   \
            float4 hv = hp[k0];                             \
            accb = fmaf(hv.x, w[k0].x, accb);               \
            accb = fmaf(hv.y, w[k0].y, accb);               \
            accb = fmaf(hv.z, w[k0].z, accb);               \
            accb = fmaf(hv.w, w[k0].w, accb);               \
        }
        DOT1A(0)   __builtin_amdgcn_sched_barrier(0);
        DOT1B(1)   __builtin_amdgcn_sched_barrier(0);
        DOT1A(2)   __builtin_amdgcn_sched_barrier(0);
        DOT1B(3)   __builtin_amdgcn_sched_barrier(0);
        DOT1A(4)   __builtin_amdgcn_sched_barrier(0);
        DOT1B(5)   __builtin_amdgcn_sched_barrier(0);
        DOT1A(6)   __builtin_amdgcn_sched_barrier(0);
        DOT1B(7)   __builtin_amdgcn_sched_barrier(0);
        DOT1A(8)   __builtin_amdgcn_sched_barrier(0);
        DOT1B(9)   __builtin_amdgcn_sched_barrier(0);
        DOT1A(10)  __builtin_amdgcn_sched_barrier(0);
        DOT1B(11)  __builtin_amdgcn_sched_barrier(0);
        DOT1A(12)  __builtin_amdgcn_sched_barrier(0);
        DOT1B(13)  __builtin_amdgcn_sched_barrier(0);
        DOT1A(14)  __builtin_amdgcn_sched_barrier(0);
        DOT1B(15)
        #undef DOT1A
        #undef DOT1B
        const float acc = acca + accb;

        // write staged x for next step (load above has drained)
        if (t < II) xst[(s + 1) & 1][t] = xnv;

        if (g == 0) {
            const float* xs = xst[s & 1];
            float xd;
            xd = xs[0] * wih0T[0][r];
            xd = fmaf(xs[1], wih0T[1][r], xd);
            xd = fmaf(xs[2], wih0T[2][r], xd);
            xd = fmaf(xs[3], wih0T[3][r], xd);
            xd = fmaf(xs[4], wih0T[4][r], xd);
            const float pre = acc + xd + bias0s[r];
            act0[r] = (gate == 2) ? tanh_f(pre) : sigm(pre);
        } else if (g == 1) {
            pB[r] = acc;
        } else {
            pC[r] = acc;
        }
        __syncthreads();                    // A: act0/pB/pC ready

        if (t < 2 * HH) {
            const int l = t & 63;
            if (t < HH) {                   // wave0: layer-0 update -> h1[s]
                if (s < TT) {
                    float iv = act0[l], fv = act0[64 + l];
                    float gv = act0[128 + l], ov = act0[192 + l];
                    c = fmaf(fv, c, iv * gv);
                    h1s[l] = ov * tanh_f(c);
                }
            } else if (s >= 1) {            // wave1: layer-1 update -> h2[s-1]
                float bi = pB[l]       + pC[l]       + bias1s[l];
                float bf = pB[64 + l]  + pC[64 + l]  + bias1s[64 + l];
                float bg = pB[128 + l] + pC[128 + l] + bias1s[128 + l];
                float bo = pB[192 + l] + pC[192 + l] + bias1s[192 + l];
                float iv = sigm(bi), fv = sigm(bf), gv = tanh_f(bg), ov = sigm(bo);
                c = fmaf(fv, c, iv * gv);
                h2s[l] = ov * tanh_f(c);
            }
        }
        __syncthreads();                    // B: h1s/h2s ready
    }

    // ---- final projection: out[b] = h2[TT-1] . W_out + b_out ----
    if (t < HH) {
        float v = h2s[t] * W_out[t];
        #pragma unroll
        for (int off = 32; off > 0; off >>= 1) v += __shfl_xor(v, off);
        if (t == 0) out[b] = v + b_out[0];
    }
}

extern "C" void kernel_launch(void* const* d_in, const int* in_sizes, int n_in,
                              void* d_out, int out_size, void* d_ws, size_t ws_size,
                              hipStream_t stream) {
    const float* x     = (const float*)d_in[0];
    const float* W_ih0 = (const float*)d_in[1];
    const float* W_hh0 = (const float*)d_in[2];
    const float* b_ih0 = (const float*)d_in[3];
    const float* b_hh0 = (const float*)d_in[4];
    const float* W_ih1 = (const float*)d_in[5];
    const float* W_hh1 = (const float*)d_in[6];
    const float* b_ih1 = (const float*)d_in[7];
    const float* b_hh1 = (const float*)d_in[8];
    const float* W_out = (const float*)d_in[9];
    const float* b_out = (const float*)d_in[10];
    float* out = (float*)d_out;

    lstm2_kernel<<<dim3(BB), dim3(NTHR), 0, stream>>>(
        x, W_ih0, W_hh0, b_ih0, b_hh0, W_ih1, W_hh1, b_ih1, b_hh1, W_out, b_out, out);
}

// Round 8
// 4918.531 us; speedup vs baseline: 3.4847x; 3.4847x over previous
//
#include <hip/hip_runtime.h>

#define TT 2048
#define BB 512
#define II 5
#define HH 64
#define NTHR 768
#define REGC 12          // float4 quads in registers = cols 0..47
#define TSTRIDE 20       // floats per wtail row: 80 B stride -> lane start-banks
                         // {0,20,8,28,16,4,24,12} tile all 32 banks, b128 conflict-free

__device__ __forceinline__ float sigm(float v)   { return 1.0f / (1.0f + __expf(-v)); }
__device__ __forceinline__ float tanh_f(float v) { return 1.0f - 2.0f / (1.0f + __expf(2.0f * v)); }

// 768 threads = 3 groups x 256 rows; one batch elem per block; grid 512;
// 2 blocks/CU. Budget law (measured R1/R4/R6/R7): {256t:112, 768t:84, 1024t:64}.
// R7 spilled at 64 reg-weights (true live ~90). R8: 48 reg-weights + 16-col
// LDS tail consumed first -> peak live ~72, slack ~12 under the 84 budget.
__global__ __launch_bounds__(NTHR, 3) void lstm2_kernel(
    const float* __restrict__ x,
    const float* __restrict__ W_ih0, const float* __restrict__ W_hh0,
    const float* __restrict__ b_ih0, const float* __restrict__ b_hh0,
    const float* __restrict__ W_ih1, const float* __restrict__ W_hh1,
    const float* __restrict__ b_ih1, const float* __restrict__ b_hh1,
    const float* __restrict__ W_out, const float* __restrict__ b_out,
    float* __restrict__ out)
{
    const int t    = threadIdx.x;
    const int b    = blockIdx.x;
    const int g    = t >> 8;        // 0: Whh0  1: Wih1  2: Whh1
    const int r    = t & 255;
    const int gate = r >> 6;        // 0=i 1=f 2=g 3=o (g0 path)

    __shared__ __align__(16) float h1s[HH];
    __shared__ __align__(16) float h2s[HH];
    __shared__ __align__(16) float act0[256];     // layer-0 gates (activated)
    __shared__ __align__(16) float pB[256];       // Wih1 . h1
    __shared__ __align__(16) float pC[256];       // Whh1 . h2
    __shared__ float bias0s[256];
    __shared__ float bias1s[256];
    __shared__ float wih0T[II][256];              // W_ih0 transposed (lane-distinct)
    __shared__ float xst[2][8];                   // staged x, double-buffered
    __shared__ __align__(16) float wtail[3 * 256 * TSTRIDE];   // 60 KB: cols 48..63

    // ---- weights: cols 0..47 in registers, cols 48..63 staged to LDS ----
    const float* Wrow = (g == 0) ? (W_hh0 + r * HH)
                       : (g == 1) ? (W_ih1 + r * HH)
                                  : (W_hh1 + r * HH);
    float4 w[REGC];
    #pragma unroll
    for (int k = 0; k < REGC; ++k) w[k] = ((const float4*)Wrow)[k];

    float* wt = wtail + (g * 256 + r) * TSTRIDE;   // 80 B row stride, 16B-aligned
    {
        const float4* q = (const float4*)(Wrow + 48);
        #pragma unroll
        for (int k = 0; k < 4; ++k) ((float4*)wt)[k] = q[k];
    }

    if (t < 256) {
        bias0s[t] = b_ih0[t] + b_hh0[t];
        bias1s[t] = b_ih1[t] + b_hh1[t];
        #pragma unroll
        for (int k = 0; k < II; ++k) wih0T[k][t] = W_ih0[t * II + k];
    }
    if (t < HH) { h1s[t] = 0.0f; h2s[t] = 0.0f; }

    const float* xb = x + (size_t)b * II;
    if (t < II) xst[0][t] = xb[t];

    float c = 0.0f;   // c1 on wave0 (t<64), c2 on wave1 (64<=t<128)
    __syncthreads();

    // Pipelined schedule (R3/R4/R7-verified): iter s computes gates0[s]
    // (vs h1[s-1]) and gates1[s-1] partials (vs h1[s-1], h2[s-2]);
    // update writes h1[s], h2[s-1]. Two barriers per step.
    for (int s = 0; s <= TT; ++s) {
        // issue next x load early (5 lanes), LDS-write late
        float xnv = 0.0f;
        if (t < II) {
            const int sn = (s + 1 < TT) ? (s + 1) : (TT - 1);
            xnv = xb[(size_t)sn * (BB * II) + t];
        }

        const float4* hp = (g == 2) ? (const float4*)h2s : (const float4*)h1s;
        float acca = 0.0f, accb = 0.0f;

        // ---- tail first (cols 48..63 from LDS): transients die before reg-dot ----
        {
            float4 w0 = ((const float4*)wt)[0];
            float4 w1 = ((const float4*)wt)[1];
            float4 h0 = hp[12], h1v = hp[13];
            acca = fmaf(h0.x, w0.x, acca);  acca = fmaf(h0.y, w0.y, acca);
            acca = fmaf(h0.z, w0.z, acca);  acca = fmaf(h0.w, w0.w, acca);
            accb = fmaf(h1v.x, w1.x, accb); accb = fmaf(h1v.y, w1.y, accb);
            accb = fmaf(h1v.z, w1.z, accb); accb = fmaf(h1v.w, w1.w, accb);
        }
        {
            float4 w2 = ((const float4*)wt)[2];
            float4 w3 = ((const float4*)wt)[3];
            float4 h2v = hp[14], h3v = hp[15];
            acca = fmaf(h2v.x, w2.x, acca); acca = fmaf(h2v.y, w2.y, acca);
            acca = fmaf(h2v.z, w2.z, acca); acca = fmaf(h2v.w, w2.w, acca);
            accb = fmaf(h3v.x, w3.x, accb); accb = fmaf(h3v.y, w3.y, accb);
            accb = fmaf(h3v.z, w3.z, accb); accb = fmaf(h3v.w, w3.w, accb);
        }

        // ---- register dot, cols 0..47 (compiler schedules freely) ----
        #pragma unroll
        for (int k = 0; k < REGC; k += 2) {
            float4 hv0 = hp[k];
            float4 hv1 = hp[k + 1];
            acca = fmaf(hv0.x, w[k].x, acca);     acca = fmaf(hv0.y, w[k].y, acca);
            acca = fmaf(hv0.z, w[k].z, acca);     acca = fmaf(hv0.w, w[k].w, acca);
            accb = fmaf(hv1.x, w[k+1].x, accb);   accb = fmaf(hv1.y, w[k+1].y, accb);
            accb = fmaf(hv1.z, w[k+1].z, accb);   accb = fmaf(hv1.w, w[k+1].w, accb);
        }
        const float acc = acca + accb;

        // write staged x for next step (load above has drained)
        if (t < II) xst[(s + 1) & 1][t] = xnv;

        if (g == 0) {
            const float* xs = xst[s & 1];
            float xd;
            xd = xs[0] * wih0T[0][r];
            xd = fmaf(xs[1], wih0T[1][r], xd);
            xd = fmaf(xs[2], wih0T[2][r], xd);
            xd = fmaf(xs[3], wih0T[3][r], xd);
            xd = fmaf(xs[4], wih0T[4][r], xd);
            const float pre = acc + xd + bias0s[r];
            act0[r] = (gate == 2) ? tanh_f(pre) : sigm(pre);
        } else if (g == 1) {
            pB[r] = acc;
        } else {
            pC[r] = acc;
        }
        __syncthreads();                    // A: act0/pB/pC ready

        if (t < 2 * HH) {
            const int l = t & 63;
            if (t < HH) {                   // wave0: layer-0 update -> h1[s]
                if (s < TT) {
                    float iv = act0[l], fv = act0[64 + l];
                    float gv = act0[128 + l], ov = act0[192 + l];
                    c = fmaf(fv, c, iv * gv);
                    h1s[l] = ov * tanh_f(c);
                }
            } else if (s >= 1) {            // wave1: layer-1 update -> h2[s-1]
                float bi = pB[l]       + pC[l]       + bias1s[l];
                float bf = pB[64 + l]  + pC[64 + l]  + bias1s[64 + l];
                float bg = pB[128 + l] + pC[128 + l] + bias1s[128 + l];
                float bo = pB[192 + l] + pC[192 + l] + bias1s[192 + l];
                float iv = sigm(bi), fv = sigm(bf), gv = tanh_f(bg), ov = sigm(bo);
                c = fmaf(fv, c, iv * gv);
                h2s[l] = ov * tanh_f(c);
            }
        }
        __syncthreads();                    // B: h1s/h2s ready
    }

    // ---- final projection: out[b] = h2[TT-1] . W_out + b_out ----
    if (t < HH) {
        float v = h2s[t] * W_out[t];
        #pragma unroll
        for (int off = 32; off > 0; off >>= 1) v += __shfl_xor(v, off);
        if (t == 0) out[b] = v + b_out[0];
    }
}

extern "C" void kernel_launch(void* const* d_in, const int* in_sizes, int n_in,
                              void* d_out, int out_size, void* d_ws, size_t ws_size,
                              hipStream_t stream) {
    const float* x     = (const float*)d_in[0];
    const float* W_ih0 = (const float*)d_in[1];
    const float* W_hh0 = (const float*)d_in[2];
    const float* b_ih0 = (const float*)d_in[3];
    const float* b_hh0 = (const float*)d_in[4];
    const float* W_ih1 = (const float*)d_in[5];
    const float* W_hh1 = (const float*)d_in[6];
    const float* b_ih1 = (const float*)d_in[7];
    const float* b_hh1 = (const float*)d_in[8];
    const float* W_out = (const float*)d_in[9];
    const float* b_out = (const float*)d_in[10];
    float* out = (float*)d_out;

    lstm2_kernel<<<dim3(BB), dim3(NTHR), 0, stream>>>(
        x, W_ih0, W_hh0, b_ih0, b_hh0, W_ih1, W_hh1, b_ih1, b_hh1, W_out, b_out, out);
}

// Round 9
// 4873.250 us; speedup vs baseline: 3.5171x; 1.0093x over previous
//
#include <hip/hip_runtime.h>

#define TT 2048
#define BB 512
#define II 5
#define HH 64
#define NTHR 768
#define REGC 12          // float4 quads in registers = cols 0..47
#define TSTRIDE 20       // floats per wtail row: 80 B stride -> lane start-banks
                         // {0,20,8,28,16,4,24,12} tile all 32 banks, b128 conflict-free

__device__ __forceinline__ float sigm(float v)   { return 1.0f / (1.0f + __expf(-v)); }
__device__ __forceinline__ float tanh_f(float v) { return 1.0f - 2.0f / (1.0f + __expf(2.0f * v)); }

// h[k] via SGPR: one lane-distinct b32 read per wave, then readlane -> the
// FMA takes the h operand from an SGPR (v_fma_f32 v,s,v). This removes the
// 16 broadcast ds_read_b128 per wave per step that R8 proved to be the
// bottleneck (broadcast b128 pays the full ~12-cyc wave64 slot).
#define RL(k) __int_as_float(__builtin_amdgcn_readlane(__float_as_int(hval), (k)))

__global__ __launch_bounds__(NTHR, 3) void lstm2_kernel(
    const float* __restrict__ x,
    const float* __restrict__ W_ih0, const float* __restrict__ W_hh0,
    const float* __restrict__ b_ih0, const float* __restrict__ b_hh0,
    const float* __restrict__ W_ih1, const float* __restrict__ W_hh1,
    const float* __restrict__ b_ih1, const float* __restrict__ b_hh1,
    const float* __restrict__ W_out, const float* __restrict__ b_out,
    float* __restrict__ out)
{
    const int t    = threadIdx.x;
    const int b    = blockIdx.x;
    const int g    = t >> 8;        // 0: Whh0  1: Wih1  2: Whh1
    const int r    = t & 255;
    const int gate = r >> 6;        // 0=i 1=f 2=g 3=o (g0 path)

    __shared__ __align__(16) float h1s[HH];
    __shared__ __align__(16) float h2s[HH];
    __shared__ __align__(16) float act0[256];     // layer-0 gates (activated)
    __shared__ __align__(16) float pB[256];       // Wih1 . h1
    __shared__ __align__(16) float pC[256];       // Whh1 . h2
    __shared__ float bias0s[256];
    __shared__ float bias1s[256];
    __shared__ float wih0T[II][256];              // W_ih0 transposed (lane-distinct)
    __shared__ float xst[2][8];                   // staged x, double-buffered
    __shared__ __align__(16) float wtail[3 * 256 * TSTRIDE];   // 60 KB: cols 48..63

    // ---- weights: cols 0..47 in registers, cols 48..63 staged to LDS ----
    const float* Wrow = (g == 0) ? (W_hh0 + r * HH)
                       : (g == 1) ? (W_ih1 + r * HH)
                                  : (W_hh1 + r * HH);
    float4 w[REGC];
    #pragma unroll
    for (int k = 0; k < REGC; ++k) w[k] = ((const float4*)Wrow)[k];

    float* wt = wtail + (g * 256 + r) * TSTRIDE;   // 80 B row stride, 16B-aligned
    {
        const float4* q = (const float4*)(Wrow + 48);
        #pragma unroll
        for (int k = 0; k < 4; ++k) ((float4*)wt)[k] = q[k];
    }

    if (t < 256) {
        bias0s[t] = b_ih0[t] + b_hh0[t];
        bias1s[t] = b_ih1[t] + b_hh1[t];
        #pragma unroll
        for (int k = 0; k < II; ++k) wih0T[k][t] = W_ih0[t * II + k];
    }
    if (t < HH) { h1s[t] = 0.0f; h2s[t] = 0.0f; }

    const float* xb = x + (size_t)b * II;
    if (t < II) xst[0][t] = xb[t];

    float c = 0.0f;   // c1 on wave0 (t<64), c2 on wave1 (64<=t<128)
    __syncthreads();

    // Pipelined schedule (R3/R4/R7/R8-verified): iter s computes gates0[s]
    // (vs h1[s-1]) and gates1[s-1] partials (vs h1[s-1], h2[s-2]);
    // update writes h1[s], h2[s-1]. Two barriers per step.
    for (int s = 0; s <= TT; ++s) {
        // issue next x load early (5 lanes), LDS-write late
        float xnv = 0.0f;
        if (t < II) {
            const int sn = (s + 1 < TT) ? (s + 1) : (TT - 1);
            xnv = xb[(size_t)sn * (BB * II) + t];
        }

        // ---- one lane-distinct read of h; all 64 h values reach the FMAs
        //      as SGPRs via readlane (no broadcast LDS traffic) ----
        const float* hsrc = (g == 2) ? h2s : h1s;
        const float hval = hsrc[t & 63];

        float acca = 0.0f, accb = 0.0f;

        // tail first (cols 48..63 from LDS): transients die before reg-dot
        {
            float4 w0 = ((const float4*)wt)[0];
            float4 w1 = ((const float4*)wt)[1];
            acca = fmaf(RL(48), w0.x, acca);  accb = fmaf(RL(49), w0.y, accb);
            acca = fmaf(RL(50), w0.z, acca);  accb = fmaf(RL(51), w0.w, accb);
            acca = fmaf(RL(52), w1.x, acca);  accb = fmaf(RL(53), w1.y, accb);
            acca = fmaf(RL(54), w1.z, acca);  accb = fmaf(RL(55), w1.w, accb);
        }
        {
            float4 w2 = ((const float4*)wt)[2];
            float4 w3 = ((const float4*)wt)[3];
            acca = fmaf(RL(56), w2.x, acca);  accb = fmaf(RL(57), w2.y, accb);
            acca = fmaf(RL(58), w2.z, acca);  accb = fmaf(RL(59), w2.w, accb);
            acca = fmaf(RL(60), w3.x, acca);  accb = fmaf(RL(61), w3.y, accb);
            acca = fmaf(RL(62), w3.z, acca);  accb = fmaf(RL(63), w3.w, accb);
        }

        // register dot, cols 0..47
        #pragma unroll
        for (int k = 0; k < REGC; ++k) {
            float4 wq = w[k];
            acca = fmaf(RL(4 * k + 0), wq.x, acca);
            accb = fmaf(RL(4 * k + 1), wq.y, accb);
            acca = fmaf(RL(4 * k + 2), wq.z, acca);
            accb = fmaf(RL(4 * k + 3), wq.w, accb);
        }
        const float acc = acca + accb;

        // write staged x for next step (load above has drained)
        if (t < II) xst[(s + 1) & 1][t] = xnv;

        if (g == 0) {
            const float* xs = xst[s & 1];
            float xd;
            xd = xs[0] * wih0T[0][r];
            xd = fmaf(xs[1], wih0T[1][r], xd);
            xd = fmaf(xs[2], wih0T[2][r], xd);
            xd = fmaf(xs[3], wih0T[3][r], xd);
            xd = fmaf(xs[4], wih0T[4][r], xd);
            const float pre = acc + xd + bias0s[r];
            act0[r] = (gate == 2) ? tanh_f(pre) : sigm(pre);
        } else if (g == 1) {
            pB[r] = acc;
        } else {
            pC[r] = acc;
        }
        __syncthreads();                    // A: act0/pB/pC ready

        if (t < 2 * HH) {
            const int l = t & 63;
            if (t < HH) {                   // wave0: layer-0 update -> h1[s]
                if (s < TT) {
                    float iv = act0[l], fv = act0[64 + l];
                    float gv = act0[128 + l], ov = act0[192 + l];
                    c = fmaf(fv, c, iv * gv);
                    h1s[l] = ov * tanh_f(c);
                }
            } else if (s >= 1) {            // wave1: layer-1 update -> h2[s-1]
                float bi = pB[l]       + pC[l]       + bias1s[l];
                float bf = pB[64 + l]  + pC[64 + l]  + bias1s[64 + l];
                float bg = pB[128 + l] + pC[128 + l] + bias1s[128 + l];
                float bo = pB[192 + l] + pC[192 + l] + bias1s[192 + l];
                float iv = sigm(bi), fv = sigm(bf), gv = tanh_f(bg), ov = sigm(bo);
                c = fmaf(fv, c, iv * gv);
                h2s[l] = ov * tanh_f(c);
            }
        }
        __syncthreads();                    // B: h1s/h2s ready
    }

    // ---- final projection: out[b] = h2[TT-1] . W_out + b_out ----
    if (t < HH) {
        float v = h2s[t] * W_out[t];
        #pragma unroll
        for (int off = 32; off > 0; off >>= 1) v += __shfl_xor(v, off);
        if (t == 0) out[b] = v + b_out[0];
    }
}

extern "C" void kernel_launch(void* const* d_in, const int* in_sizes, int n_in,
                              void* d_out, int out_size, void* d_ws, size_t ws_size,
                              hipStream_t stream) {
    const float* x     = (const float*)d_in[0];
    const float* W_ih0 = (const float*)d_in[1];
    const float* W_hh0 = (const float*)d_in[2];
    const float* b_ih0 = (const float*)d_in[3];
    const float* b_hh0 = (const float*)d_in[4];
    const float* W_ih1 = (const float*)d_in[5];
    const float* W_hh1 = (const float*)d_in[6];
    const float* b_ih1 = (const float*)d_in[7];
    const float* b_hh1 = (const float*)d_in[8];
    const float* W_out = (const float*)d_in[9];
    const float* b_out = (const float*)d_in[10];
    float* out = (float*)d_out;

    lstm2_kernel<<<dim3(BB), dim3(NTHR), 0, stream>>>(
        x, W_ih0, W_hh0, b_ih0, b_hh0, W_ih1, W_hh1, b_ih1, b_hh1, W_out, b_out, out);
}